// Round 1
// baseline (2837.109 us; speedup 1.0000x reference)
//
#include <hip/hip_runtime.h>
#include <math.h>

constexpr int D = 128;

// ---------------------------------------------------------------------------
// K1: per-edge scatter with on-the-fly logmap0.
// 32 lanes per edge; lane l owns floats [4l, 4l+4) of the source row.
// msg[dst] += arctanh(||x_src||)/||x_src|| * x_src   (fp32 hardware atomics)
// deg[dst] += 1
// ---------------------------------------------------------------------------
__global__ __launch_bounds__(256) void edge_scatter_kernel(
    const float* __restrict__ x,
    const int* __restrict__ src,
    const int* __restrict__ dst,
    float* __restrict__ msg,
    float* __restrict__ deg,
    int nEdges)
{
    long long t = (long long)blockIdx.x * blockDim.x + threadIdx.x;
    int edge = (int)(t >> 5);
    int lane = (int)(t & 31);
    if (edge >= nEdges) return;

    int s = src[edge];
    int d = dst[edge];

    const float4 xv = *reinterpret_cast<const float4*>(x + (size_t)s * D + lane * 4);
    float ss = xv.x * xv.x + xv.y * xv.y + xv.z * xv.z + xv.w * xv.w;
    // reduce over the 32-lane group (masks <32 stay within each half-wave)
    ss += __shfl_xor(ss, 1);
    ss += __shfl_xor(ss, 2);
    ss += __shfl_xor(ss, 4);
    ss += __shfl_xor(ss, 8);
    ss += __shfl_xor(ss, 16);

    float norm = sqrtf(ss);
    float ncl  = fminf(norm, 1.0f - 1e-7f);
    float at   = 0.5f * logf((1.0f + ncl) / (1.0f - ncl));  // arctanh
    float scale = at / fmaxf(norm, 1e-15f);

    float* mrow = msg + (size_t)d * D + lane * 4;
    unsafeAtomicAdd(mrow + 0, xv.x * scale);
    unsafeAtomicAdd(mrow + 1, xv.y * scale);
    unsafeAtomicAdd(mrow + 2, xv.z * scale);
    unsafeAtomicAdd(mrow + 3, xv.w * scale);
    if (lane == 0) unsafeAtomicAdd(deg + d, 1.0f);
}

// ---------------------------------------------------------------------------
// K2: out = expmap0( (msg/max(deg,1)) @ W^T + b ), zeroed where deg==0.
// Tile: 64 rows x 128 cols, BK=64, 256 threads, each thread 4 rows x 8 cols.
// sA row-major (scalar broadcast reads), sW k-major (float4 reads).
// NOTE: msg may alias out — all reads of a block's rows complete (staged into
// LDS + acc dependency chain) before that block stores the same rows.
// ---------------------------------------------------------------------------
__global__ __launch_bounds__(256) void gemm_expmap_kernel(
    const float* msg,
    const float* __restrict__ deg,
    const float* __restrict__ W,
    const float* __restrict__ bias,
    float* out,
    int nNodes)
{
    __shared__ float sA[64][68];    // [m][k], stride 68 keeps float4 alignment
    __shared__ float sW[64][132];   // [k][j]

    const int t  = threadIdx.x;
    const int tx = t & 15;   // col group: cols [8*tx, 8*tx+8)
    const int ty = t >> 4;   // row group: rows [4*ty, 4*ty+4)
    const int m0 = blockIdx.x * 64;

    float acc[4][8];
#pragma unroll
    for (int i = 0; i < 4; ++i)
#pragma unroll
        for (int j = 0; j < 8; ++j) acc[i][j] = 0.0f;

    for (int kc = 0; kc < D; kc += 64) {
        // stage A: 16 rows per pass, lane covers 16B of k
#pragma unroll
        for (int p = 0; p < 4; ++p) {
            int ml = p * 16 + ty;
            int kl = tx * 4;
            int m  = m0 + ml;
            float4 v = make_float4(0.f, 0.f, 0.f, 0.f);
            if (m < nNodes) {
                v = *reinterpret_cast<const float4*>(msg + (size_t)m * D + kc + kl);
                float inv = 1.0f / fmaxf(deg[m], 1.0f);
                v.x *= inv; v.y *= inv; v.z *= inv; v.w *= inv;
            }
            *reinterpret_cast<float4*>(&sA[ml][kl]) = v;
        }
        // stage W transposed: sW[k][j] = W[j][kc+k]
#pragma unroll
        for (int p = 0; p < 8; ++p) {
            int j  = p * 16 + ty;
            int kl = tx * 4;
            float4 v = *reinterpret_cast<const float4*>(W + (size_t)j * D + kc + kl);
            sW[kl + 0][j] = v.x;
            sW[kl + 1][j] = v.y;
            sW[kl + 2][j] = v.z;
            sW[kl + 3][j] = v.w;
        }
        __syncthreads();

        for (int k = 0; k < 64; ++k) {
            float a_[4];
#pragma unroll
            for (int i = 0; i < 4; ++i) a_[i] = sA[ty * 4 + i][k];
            float4 w0 = *reinterpret_cast<const float4*>(&sW[k][tx * 8]);
            float4 w1 = *reinterpret_cast<const float4*>(&sW[k][tx * 8 + 4]);
            float w_[8] = {w0.x, w0.y, w0.z, w0.w, w1.x, w1.y, w1.z, w1.w};
#pragma unroll
            for (int i = 0; i < 4; ++i)
#pragma unroll
                for (int j = 0; j < 8; ++j) acc[i][j] += a_[i] * w_[j];
        }
        __syncthreads();
    }

    // epilogue: + bias, row norm across the 16-lane col group, tanh scale
    float4 b0 = *reinterpret_cast<const float4*>(bias + tx * 8);
    float4 b1 = *reinterpret_cast<const float4*>(bias + tx * 8 + 4);
    float bv[8] = {b0.x, b0.y, b0.z, b0.w, b1.x, b1.y, b1.z, b1.w};

#pragma unroll
    for (int i = 0; i < 4; ++i) {
        int m = m0 + ty * 4 + i;          // uniform across the 16-lane group
        if (m >= nNodes) continue;
        float dg = deg[m];
        float v[8];
        float ss = 0.0f;
#pragma unroll
        for (int j = 0; j < 8; ++j) {
            v[j] = acc[i][j] + bv[j];
            ss += v[j] * v[j];
        }
        // sum over 16 lanes holding this row
        ss += __shfl_xor(ss, 1);
        ss += __shfl_xor(ss, 2);
        ss += __shfl_xor(ss, 4);
        ss += __shfl_xor(ss, 8);
        float norm = sqrtf(ss);
        float scale = (dg > 0.0f) ? (tanhf(norm) / fmaxf(norm, 1e-15f)) : 0.0f;

        float4 o0 = make_float4(v[0] * scale, v[1] * scale, v[2] * scale, v[3] * scale);
        float4 o1 = make_float4(v[4] * scale, v[5] * scale, v[6] * scale, v[7] * scale);
        *reinterpret_cast<float4*>(out + (size_t)m * D + tx * 8)     = o0;
        *reinterpret_cast<float4*>(out + (size_t)m * D + tx * 8 + 4) = o1;
    }
}

extern "C" void kernel_launch(void* const* d_in, const int* in_sizes, int n_in,
                              void* d_out, int out_size, void* d_ws, size_t ws_size,
                              hipStream_t stream) {
    const float* x   = (const float*)d_in[0];
    const float* W   = (const float*)d_in[1];
    const float* b   = (const float*)d_in[2];
    const int*   src = (const int*)d_in[3];
    const int*   dst = (const int*)d_in[4];
    float* out = (float*)d_out;

    int nNodes = in_sizes[0] / D;
    int nEdges = in_sizes[3];

    float* msg = out;            // accumulate messages directly in d_out
    float* deg = (float*)d_ws;   // nNodes floats of scratch

    hipMemsetAsync(msg, 0, (size_t)nNodes * D * sizeof(float), stream);
    hipMemsetAsync(deg, 0, (size_t)nNodes * sizeof(float), stream);

    {
        long long threads = (long long)nEdges * 32;
        int blocks = (int)((threads + 255) / 256);
        edge_scatter_kernel<<<blocks, 256, 0, stream>>>(x, src, dst, msg, deg, nEdges);
    }
    {
        int blocks = (nNodes + 63) / 64;
        gemm_expmap_kernel<<<blocks, 256, 0, stream>>>(msg, deg, W, b, out, nNodes);
    }
}

// Round 2
// 376.832 us; speedup vs baseline: 7.5288x; 7.5288x over previous
//
#include <hip/hip_runtime.h>
#include <math.h>

constexpr int D = 128;

// ===========================================================================
// CSR build: histogram -> two-level exclusive scan -> scatter edge sources
// ===========================================================================
__global__ __launch_bounds__(256) void hist_kernel(
    const int* __restrict__ dst, int* __restrict__ count, int nEdges)
{
    int stride = gridDim.x * blockDim.x;
    for (int i = blockIdx.x * blockDim.x + threadIdx.x; i < nEdges; i += stride)
        atomicAdd(&count[dst[i]], 1);
}

// 1024 elements per block (256 threads x 4): exclusive scan within block,
// block total to blksums.
__global__ __launch_bounds__(256) void scan_block_kernel(
    const int* __restrict__ count, int* __restrict__ rowptr,
    int* __restrict__ blksums, int n)
{
    __shared__ int sums[256];
    int t = threadIdx.x;
    int base = blockIdx.x * 1024 + t * 4;
    int v[4];
    int s = 0;
#pragma unroll
    for (int j = 0; j < 4; ++j) { v[j] = (base + j < n) ? count[base + j] : 0; s += v[j]; }
    sums[t] = s;
    __syncthreads();
    for (int off = 1; off < 256; off <<= 1) {
        int xv = (t >= off) ? sums[t - off] : 0;
        __syncthreads();
        if (t >= off) sums[t] += xv;
        __syncthreads();
    }
    int run = (t > 0) ? sums[t - 1] : 0;
#pragma unroll
    for (int j = 0; j < 4; ++j) { if (base + j < n) rowptr[base + j] = run; run += v[j]; }
    if (t == 255) blksums[blockIdx.x] = sums[255];
}

// single block: exclusive scan of per-block totals (numBlocks <= 256)
__global__ __launch_bounds__(256) void scan_totals_kernel(
    int* __restrict__ blksums, int* __restrict__ rowptr,
    int numBlocks, int n, int E)
{
    __shared__ int s[256];
    int t = threadIdx.x;
    s[t] = (t < numBlocks) ? blksums[t] : 0;
    __syncthreads();
    for (int off = 1; off < 256; off <<= 1) {
        int xv = (t >= off) ? s[t - off] : 0;
        __syncthreads();
        if (t >= off) s[t] += xv;
        __syncthreads();
    }
    if (t < numBlocks) blksums[t] = (t > 0) ? s[t - 1] : 0;
    if (t == 0) rowptr[n] = E;
}

__global__ __launch_bounds__(256) void add_offsets_kernel(
    int* __restrict__ rowptr, const int* __restrict__ blksums, int n)
{
    int i = blockIdx.x * 256 + threadIdx.x;
    if (i < n) rowptr[i] += blksums[i >> 10];
}

__global__ __launch_bounds__(256) void fill_kernel(
    const int* __restrict__ src, const int* __restrict__ dst,
    const int* __restrict__ rowptr, int* __restrict__ fill,
    int* __restrict__ csr_src, int nEdges)
{
    int stride = gridDim.x * blockDim.x;
    for (int i = blockIdx.x * blockDim.x + threadIdx.x; i < nEdges; i += stride) {
        int d = dst[i];
        int pos = rowptr[d] + atomicAdd(&fill[d], 1);
        csr_src[pos] = src[i];
    }
}

// ===========================================================================
// scale[n] = arctanh(clip(||x_n||)) / max(||x_n||, eps)   (one wave per node)
// ===========================================================================
__global__ __launch_bounds__(256) void scale_kernel(
    const float* __restrict__ x, float* __restrict__ scale, int nNodes)
{
    int node = (blockIdx.x * 256 + threadIdx.x) >> 6;
    int lane = threadIdx.x & 63;
    if (node >= nNodes) return;
    float2 xv = *reinterpret_cast<const float2*>(x + (size_t)node * D + lane * 2);
    float ss = xv.x * xv.x + xv.y * xv.y;
    ss += __shfl_xor(ss, 1);
    ss += __shfl_xor(ss, 2);
    ss += __shfl_xor(ss, 4);
    ss += __shfl_xor(ss, 8);
    ss += __shfl_xor(ss, 16);
    ss += __shfl_xor(ss, 32);
    if (lane == 0) {
        float norm = sqrtf(ss);
        float ncl  = fminf(norm, 1.0f - 1e-7f);
        float at   = 0.5f * logf((1.0f + ncl) / (1.0f - ncl));
        scale[node] = at / fmaxf(norm, 1e-15f);
    }
}

// ===========================================================================
// gather: msg[n] = sum_{e in in(n)} scale[src_e] * x[src_e]; degf[n] = deg
// One wave (=one 64-thread block) per node; lane owns float2 of D.
// Block-uniform csr/rowptr/scale loads let the compiler scalarize them.
// ===========================================================================
__global__ __launch_bounds__(64) void gather_kernel(
    const float* __restrict__ x, const float* __restrict__ scale,
    const int* __restrict__ csr_src, const int* __restrict__ rowptr,
    float* __restrict__ msg, float* __restrict__ degf)
{
    int n    = blockIdx.x;
    int lane = threadIdx.x;
    int beg = rowptr[n], end = rowptr[n + 1];
    float2 acc = make_float2(0.0f, 0.0f);
    int e = beg;
    for (; e + 1 < end; e += 2) {
        int s0 = csr_src[e];
        int s1 = csr_src[e + 1];
        float sc0 = scale[s0];
        float sc1 = scale[s1];
        float2 a = *reinterpret_cast<const float2*>(x + (size_t)s0 * D + lane * 2);
        float2 b = *reinterpret_cast<const float2*>(x + (size_t)s1 * D + lane * 2);
        acc.x += sc0 * a.x;  acc.y += sc0 * a.y;
        acc.x += sc1 * b.x;  acc.y += sc1 * b.y;
    }
    if (e < end) {
        int s0 = csr_src[e];
        float sc0 = scale[s0];
        float2 a = *reinterpret_cast<const float2*>(x + (size_t)s0 * D + lane * 2);
        acc.x += sc0 * a.x;  acc.y += sc0 * a.y;
    }
    *reinterpret_cast<float2*>(msg + (size_t)n * D + lane * 2) = acc;
    if (lane == 0) degf[n] = (float)(end - beg);
}

// ===========================================================================
// Fallback edge scatter (fp32 hardware atomics) — used only if ws too small.
// ===========================================================================
__global__ __launch_bounds__(256) void edge_scatter_kernel(
    const float* __restrict__ x,
    const int* __restrict__ src,
    const int* __restrict__ dst,
    float* __restrict__ msg,
    float* __restrict__ deg,
    int nEdges)
{
    long long t = (long long)blockIdx.x * blockDim.x + threadIdx.x;
    int edge = (int)(t >> 5);
    int lane = (int)(t & 31);
    if (edge >= nEdges) return;

    int s = src[edge];
    int d = dst[edge];

    const float4 xv = *reinterpret_cast<const float4*>(x + (size_t)s * D + lane * 4);
    float ss = xv.x * xv.x + xv.y * xv.y + xv.z * xv.z + xv.w * xv.w;
    ss += __shfl_xor(ss, 1);
    ss += __shfl_xor(ss, 2);
    ss += __shfl_xor(ss, 4);
    ss += __shfl_xor(ss, 8);
    ss += __shfl_xor(ss, 16);

    float norm = sqrtf(ss);
    float ncl  = fminf(norm, 1.0f - 1e-7f);
    float at   = 0.5f * logf((1.0f + ncl) / (1.0f - ncl));
    float scale = at / fmaxf(norm, 1e-15f);

    float* mrow = msg + (size_t)d * D + lane * 4;
    unsafeAtomicAdd(mrow + 0, xv.x * scale);
    unsafeAtomicAdd(mrow + 1, xv.y * scale);
    unsafeAtomicAdd(mrow + 2, xv.z * scale);
    unsafeAtomicAdd(mrow + 3, xv.w * scale);
    if (lane == 0) unsafeAtomicAdd(deg + d, 1.0f);
}

// ===========================================================================
// GEMM + expmap: out = expmap0( (msg/max(deg,1)) @ W^T + b ), 0 where deg==0
// ===========================================================================
__global__ __launch_bounds__(256) void gemm_expmap_kernel(
    const float* msg,
    const float* __restrict__ deg,
    const float* __restrict__ W,
    const float* __restrict__ bias,
    float* out,
    int nNodes)
{
    __shared__ float sA[64][68];
    __shared__ float sW[64][132];

    const int t  = threadIdx.x;
    const int tx = t & 15;
    const int ty = t >> 4;
    const int m0 = blockIdx.x * 64;

    float acc[4][8];
#pragma unroll
    for (int i = 0; i < 4; ++i)
#pragma unroll
        for (int j = 0; j < 8; ++j) acc[i][j] = 0.0f;

    for (int kc = 0; kc < D; kc += 64) {
#pragma unroll
        for (int p = 0; p < 4; ++p) {
            int ml = p * 16 + ty;
            int kl = tx * 4;
            int m  = m0 + ml;
            float4 v = make_float4(0.f, 0.f, 0.f, 0.f);
            if (m < nNodes) {
                v = *reinterpret_cast<const float4*>(msg + (size_t)m * D + kc + kl);
                float inv = 1.0f / fmaxf(deg[m], 1.0f);
                v.x *= inv; v.y *= inv; v.z *= inv; v.w *= inv;
            }
            *reinterpret_cast<float4*>(&sA[ml][kl]) = v;
        }
#pragma unroll
        for (int p = 0; p < 8; ++p) {
            int j  = p * 16 + ty;
            int kl = tx * 4;
            float4 v = *reinterpret_cast<const float4*>(W + (size_t)j * D + kc + kl);
            sW[kl + 0][j] = v.x;
            sW[kl + 1][j] = v.y;
            sW[kl + 2][j] = v.z;
            sW[kl + 3][j] = v.w;
        }
        __syncthreads();

        for (int k = 0; k < 64; ++k) {
            float a_[4];
#pragma unroll
            for (int i = 0; i < 4; ++i) a_[i] = sA[ty * 4 + i][k];
            float4 w0 = *reinterpret_cast<const float4*>(&sW[k][tx * 8]);
            float4 w1 = *reinterpret_cast<const float4*>(&sW[k][tx * 8 + 4]);
            float w_[8] = {w0.x, w0.y, w0.z, w0.w, w1.x, w1.y, w1.z, w1.w};
#pragma unroll
            for (int i = 0; i < 4; ++i)
#pragma unroll
                for (int j = 0; j < 8; ++j) acc[i][j] += a_[i] * w_[j];
        }
        __syncthreads();
    }

    float4 b0 = *reinterpret_cast<const float4*>(bias + tx * 8);
    float4 b1 = *reinterpret_cast<const float4*>(bias + tx * 8 + 4);
    float bv[8] = {b0.x, b0.y, b0.z, b0.w, b1.x, b1.y, b1.z, b1.w};

#pragma unroll
    for (int i = 0; i < 4; ++i) {
        int m = m0 + ty * 4 + i;
        if (m >= nNodes) continue;
        float dg = deg[m];
        float v[8];
        float ss = 0.0f;
#pragma unroll
        for (int j = 0; j < 8; ++j) {
            v[j] = acc[i][j] + bv[j];
            ss += v[j] * v[j];
        }
        ss += __shfl_xor(ss, 1);
        ss += __shfl_xor(ss, 2);
        ss += __shfl_xor(ss, 4);
        ss += __shfl_xor(ss, 8);
        float norm = sqrtf(ss);
        float scale = (dg > 0.0f) ? (tanhf(norm) / fmaxf(norm, 1e-15f)) : 0.0f;

        float4 o0 = make_float4(v[0] * scale, v[1] * scale, v[2] * scale, v[3] * scale);
        float4 o1 = make_float4(v[4] * scale, v[5] * scale, v[6] * scale, v[7] * scale);
        *reinterpret_cast<float4*>(out + (size_t)m * D + tx * 8)     = o0;
        *reinterpret_cast<float4*>(out + (size_t)m * D + tx * 8 + 4) = o1;
    }
}

static inline size_t align256(size_t o) { return (o + 255) & ~(size_t)255; }

extern "C" void kernel_launch(void* const* d_in, const int* in_sizes, int n_in,
                              void* d_out, int out_size, void* d_ws, size_t ws_size,
                              hipStream_t stream) {
    const float* x   = (const float*)d_in[0];
    const float* W   = (const float*)d_in[1];
    const float* b   = (const float*)d_in[2];
    const int*   src = (const int*)d_in[3];
    const int*   dst = (const int*)d_in[4];
    float* out = (float*)d_out;

    int nNodes = in_sizes[0] / D;
    int nEdges = in_sizes[3];

    // workspace layout
    char* ws = (char*)d_ws;
    size_t off = 0;
    float* degf    = (float*)(ws + off); off = align256(off + sizeof(float) * nNodes);
    int*   count   = (int*)  (ws + off); off = align256(off + sizeof(int) * nNodes);
    int*   rowptr  = (int*)  (ws + off); off = align256(off + sizeof(int) * (nNodes + 1));
    int*   fill    = (int*)  (ws + off); off = align256(off + sizeof(int) * nNodes);
    float* scl     = (float*)(ws + off); off = align256(off + sizeof(float) * nNodes);
    int*   blksums = (int*)  (ws + off); off = align256(off + sizeof(int) * 256);
    int*   csr_src = (int*)  (ws + off); off = align256(off + sizeof(int) * nEdges);
    size_t required = off;

    float* msg = out;  // accumulate / stage messages directly in d_out

    int numScanBlocks = (nNodes + 1023) / 1024;

    if (ws_size >= required && numScanBlocks <= 256) {
        // ---- CSR path (no float atomics) ----
        hipMemsetAsync(count, 0, sizeof(int) * nNodes, stream);
        hipMemsetAsync(fill,  0, sizeof(int) * nNodes, stream);

        int egrid = min(2048, (nEdges + 255) / 256);
        hist_kernel<<<egrid, 256, 0, stream>>>(dst, count, nEdges);
        scan_block_kernel<<<numScanBlocks, 256, 0, stream>>>(count, rowptr, blksums, nNodes);
        scan_totals_kernel<<<1, 256, 0, stream>>>(blksums, rowptr, numScanBlocks, nNodes, nEdges);
        add_offsets_kernel<<<(nNodes + 255) / 256, 256, 0, stream>>>(rowptr, blksums, nNodes);
        fill_kernel<<<egrid, 256, 0, stream>>>(src, dst, rowptr, fill, csr_src, nEdges);

        scale_kernel<<<(nNodes + 3) / 4, 256, 0, stream>>>(x, scl, nNodes);
        gather_kernel<<<nNodes, 64, 0, stream>>>(x, scl, csr_src, rowptr, msg, degf);
    } else {
        // ---- fallback: fp32 atomic scatter ----
        float* deg = (float*)d_ws;
        hipMemsetAsync(msg, 0, (size_t)nNodes * D * sizeof(float), stream);
        hipMemsetAsync(deg, 0, (size_t)nNodes * sizeof(float), stream);
        long long threads = (long long)nEdges * 32;
        int blocks = (int)((threads + 255) / 256);
        edge_scatter_kernel<<<blocks, 256, 0, stream>>>(x, src, dst, msg, (float*)d_ws, nEdges);
        degf = (float*)d_ws;
    }

    gemm_expmap_kernel<<<(nNodes + 63) / 64, 256, 0, stream>>>(msg, degf, W, b, out, nNodes);
}

// Round 3
// 354.759 us; speedup vs baseline: 7.9973x; 1.0622x over previous
//
#include <hip/hip_runtime.h>
#include <math.h>

constexpr int D = 128;

// ===========================================================================
// CSR build: histogram -> two-level exclusive scan -> XCD-partitioned scatter
// ===========================================================================
__global__ __launch_bounds__(256) void hist_kernel(
    const int* __restrict__ dst, int* __restrict__ count, int nEdges)
{
    int stride = gridDim.x * blockDim.x;
    for (int i = blockIdx.x * blockDim.x + threadIdx.x; i < nEdges; i += stride)
        atomicAdd(&count[dst[i]], 1);
}

__global__ __launch_bounds__(256) void scan_block_kernel(
    const int* __restrict__ count, int* __restrict__ rowptr,
    int* __restrict__ blksums, int n)
{
    __shared__ int sums[256];
    int t = threadIdx.x;
    int base = blockIdx.x * 1024 + t * 4;
    int v[4];
    int s = 0;
#pragma unroll
    for (int j = 0; j < 4; ++j) { v[j] = (base + j < n) ? count[base + j] : 0; s += v[j]; }
    sums[t] = s;
    __syncthreads();
    for (int off = 1; off < 256; off <<= 1) {
        int xv = (t >= off) ? sums[t - off] : 0;
        __syncthreads();
        if (t >= off) sums[t] += xv;
        __syncthreads();
    }
    int run = (t > 0) ? sums[t - 1] : 0;
#pragma unroll
    for (int j = 0; j < 4; ++j) { if (base + j < n) rowptr[base + j] = run; run += v[j]; }
    if (t == 255) blksums[blockIdx.x] = sums[255];
}

__global__ __launch_bounds__(256) void scan_totals_kernel(
    int* __restrict__ blksums, int* __restrict__ rowptr,
    int numBlocks, int n, int E)
{
    __shared__ int s[256];
    int t = threadIdx.x;
    s[t] = (t < numBlocks) ? blksums[t] : 0;
    __syncthreads();
    for (int off = 1; off < 256; off <<= 1) {
        int xv = (t >= off) ? s[t - off] : 0;
        __syncthreads();
        if (t >= off) s[t] += xv;
        __syncthreads();
    }
    if (t < numBlocks) blksums[t] = (t > 0) ? s[t - 1] : 0;
    if (t == 0) rowptr[n] = E;
}

__global__ __launch_bounds__(256) void add_offsets_kernel(
    int* __restrict__ rowptr, const int* __restrict__ blksums, int n)
{
    int i = blockIdx.x * 256 + threadIdx.x;
    if (i < n) rowptr[i] += blksums[i >> 10];
}

// XCD-partitioned fill: blocks with (blockIdx&7)==p only scatter edges whose
// dst lies in window p. All writes to a csr window then come from one XCD's
// L2 (blockIdx%8 -> XCD round-robin), killing the 64B/store write
// amplification. Each edge is written exactly once regardless of mapping.
__global__ __launch_bounds__(256) void fill_kernel(
    const int* __restrict__ src, const int* __restrict__ dst,
    const int* __restrict__ rowptr, int* __restrict__ fill,
    int* __restrict__ csr_src, int nEdges, int winSize)
{
    int pass  = blockIdx.x & 7;
    int slice = blockIdx.x >> 3;
    int nSlices = gridDim.x >> 3;
    int lo = pass * winSize;
    int hi = lo + winSize;

    int stride = nSlices * blockDim.x;
    for (int i = slice * blockDim.x + threadIdx.x; i < nEdges; i += stride) {
        int d = dst[i];
        if (d >= lo && d < hi) {
            int pos = rowptr[d] + atomicAdd(&fill[d], 1);
            csr_src[pos] = src[i];
        }
    }
}

// ===========================================================================
// scale[n] = arctanh(clip(||x_n||)) / max(||x_n||, eps)   (one wave per node)
// ===========================================================================
__global__ __launch_bounds__(256) void scale_kernel(
    const float* __restrict__ x, float* __restrict__ scale, int nNodes)
{
    int node = (blockIdx.x * 256 + threadIdx.x) >> 6;
    int lane = threadIdx.x & 63;
    if (node >= nNodes) return;
    float2 xv = *reinterpret_cast<const float2*>(x + (size_t)node * D + lane * 2);
    float ss = xv.x * xv.x + xv.y * xv.y;
    ss += __shfl_xor(ss, 1);
    ss += __shfl_xor(ss, 2);
    ss += __shfl_xor(ss, 4);
    ss += __shfl_xor(ss, 8);
    ss += __shfl_xor(ss, 16);
    ss += __shfl_xor(ss, 32);
    if (lane == 0) {
        float norm = sqrtf(ss);
        float ncl  = fminf(norm, 1.0f - 1e-7f);
        float at   = 0.5f * logf((1.0f + ncl) / (1.0f - ncl));
        scale[node] = at / fmaxf(norm, 1e-15f);
    }
}

// ===========================================================================
// gather: msg[n] = sum_{e in in(n)} scale[src_e] * x[src_e]; degf[n] = deg
// 4 nodes per 256-thread block (one wave each); lane owns float2 of D.
// ===========================================================================
__global__ __launch_bounds__(256) void gather_kernel(
    const float* __restrict__ x, const float* __restrict__ scale,
    const int* __restrict__ csr_src, const int* __restrict__ rowptr,
    float* __restrict__ msg, float* __restrict__ degf, int nNodes)
{
    int n    = blockIdx.x * 4 + (threadIdx.x >> 6);
    int lane = threadIdx.x & 63;
    if (n >= nNodes) return;

    int beg = rowptr[n], end = rowptr[n + 1];
    float2 acc0 = make_float2(0.0f, 0.0f);
    float2 acc1 = make_float2(0.0f, 0.0f);
    int e = beg;
    for (; e + 3 < end; e += 4) {
        int s0 = csr_src[e],     s1 = csr_src[e + 1];
        int s2 = csr_src[e + 2], s3 = csr_src[e + 3];
        float sc0 = scale[s0], sc1 = scale[s1];
        float sc2 = scale[s2], sc3 = scale[s3];
        float2 a = *reinterpret_cast<const float2*>(x + (size_t)s0 * D + lane * 2);
        float2 b = *reinterpret_cast<const float2*>(x + (size_t)s1 * D + lane * 2);
        float2 c = *reinterpret_cast<const float2*>(x + (size_t)s2 * D + lane * 2);
        float2 d = *reinterpret_cast<const float2*>(x + (size_t)s3 * D + lane * 2);
        acc0.x += sc0 * a.x;  acc0.y += sc0 * a.y;
        acc1.x += sc1 * b.x;  acc1.y += sc1 * b.y;
        acc0.x += sc2 * c.x;  acc0.y += sc2 * c.y;
        acc1.x += sc3 * d.x;  acc1.y += sc3 * d.y;
    }
    for (; e < end; ++e) {
        int s0 = csr_src[e];
        float sc0 = scale[s0];
        float2 a = *reinterpret_cast<const float2*>(x + (size_t)s0 * D + lane * 2);
        acc0.x += sc0 * a.x;  acc0.y += sc0 * a.y;
    }
    acc0.x += acc1.x;  acc0.y += acc1.y;
    *reinterpret_cast<float2*>(msg + (size_t)n * D + lane * 2) = acc0;
    if (lane == 0) degf[n] = (float)(end - beg);
}

// ===========================================================================
// Fallback edge scatter (fp32 hardware atomics) — used only if ws too small.
// ===========================================================================
__global__ __launch_bounds__(256) void edge_scatter_kernel(
    const float* __restrict__ x,
    const int* __restrict__ src,
    const int* __restrict__ dst,
    float* __restrict__ msg,
    float* __restrict__ deg,
    int nEdges)
{
    long long t = (long long)blockIdx.x * blockDim.x + threadIdx.x;
    int edge = (int)(t >> 5);
    int lane = (int)(t & 31);
    if (edge >= nEdges) return;

    int s = src[edge];
    int d = dst[edge];

    const float4 xv = *reinterpret_cast<const float4*>(x + (size_t)s * D + lane * 4);
    float ss = xv.x * xv.x + xv.y * xv.y + xv.z * xv.z + xv.w * xv.w;
    ss += __shfl_xor(ss, 1);
    ss += __shfl_xor(ss, 2);
    ss += __shfl_xor(ss, 4);
    ss += __shfl_xor(ss, 8);
    ss += __shfl_xor(ss, 16);

    float norm = sqrtf(ss);
    float ncl  = fminf(norm, 1.0f - 1e-7f);
    float at   = 0.5f * logf((1.0f + ncl) / (1.0f - ncl));
    float scale = at / fmaxf(norm, 1e-15f);

    float* mrow = msg + (size_t)d * D + lane * 4;
    unsafeAtomicAdd(mrow + 0, xv.x * scale);
    unsafeAtomicAdd(mrow + 1, xv.y * scale);
    unsafeAtomicAdd(mrow + 2, xv.z * scale);
    unsafeAtomicAdd(mrow + 3, xv.w * scale);
    if (lane == 0) unsafeAtomicAdd(deg + d, 1.0f);
}

// ===========================================================================
// GEMM + expmap: out = expmap0( (msg/max(deg,1)) @ W^T + b ), 0 where deg==0
// ===========================================================================
__global__ __launch_bounds__(256) void gemm_expmap_kernel(
    const float* msg,
    const float* __restrict__ deg,
    const float* __restrict__ W,
    const float* __restrict__ bias,
    float* out,
    int nNodes)
{
    __shared__ float sA[64][68];
    __shared__ float sW[64][132];

    const int t  = threadIdx.x;
    const int tx = t & 15;
    const int ty = t >> 4;
    const int m0 = blockIdx.x * 64;

    float acc[4][8];
#pragma unroll
    for (int i = 0; i < 4; ++i)
#pragma unroll
        for (int j = 0; j < 8; ++j) acc[i][j] = 0.0f;

    for (int kc = 0; kc < D; kc += 64) {
#pragma unroll
        for (int p = 0; p < 4; ++p) {
            int ml = p * 16 + ty;
            int kl = tx * 4;
            int m  = m0 + ml;
            float4 v = make_float4(0.f, 0.f, 0.f, 0.f);
            if (m < nNodes) {
                v = *reinterpret_cast<const float4*>(msg + (size_t)m * D + kc + kl);
                float inv = 1.0f / fmaxf(deg[m], 1.0f);
                v.x *= inv; v.y *= inv; v.z *= inv; v.w *= inv;
            }
            *reinterpret_cast<float4*>(&sA[ml][kl]) = v;
        }
#pragma unroll
        for (int p = 0; p < 8; ++p) {
            int j  = p * 16 + ty;
            int kl = tx * 4;
            float4 v = *reinterpret_cast<const float4*>(W + (size_t)j * D + kc + kl);
            sW[kl + 0][j] = v.x;
            sW[kl + 1][j] = v.y;
            sW[kl + 2][j] = v.z;
            sW[kl + 3][j] = v.w;
        }
        __syncthreads();

        for (int k = 0; k < 64; ++k) {
            float a_[4];
#pragma unroll
            for (int i = 0; i < 4; ++i) a_[i] = sA[ty * 4 + i][k];
            float4 w0 = *reinterpret_cast<const float4*>(&sW[k][tx * 8]);
            float4 w1 = *reinterpret_cast<const float4*>(&sW[k][tx * 8 + 4]);
            float w_[8] = {w0.x, w0.y, w0.z, w0.w, w1.x, w1.y, w1.z, w1.w};
#pragma unroll
            for (int i = 0; i < 4; ++i)
#pragma unroll
                for (int j = 0; j < 8; ++j) acc[i][j] += a_[i] * w_[j];
        }
        __syncthreads();
    }

    float4 b0 = *reinterpret_cast<const float4*>(bias + tx * 8);
    float4 b1 = *reinterpret_cast<const float4*>(bias + tx * 8 + 4);
    float bv[8] = {b0.x, b0.y, b0.z, b0.w, b1.x, b1.y, b1.z, b1.w};

#pragma unroll
    for (int i = 0; i < 4; ++i) {
        int m = m0 + ty * 4 + i;
        if (m >= nNodes) continue;
        float dg = deg[m];
        float v[8];
        float ss = 0.0f;
#pragma unroll
        for (int j = 0; j < 8; ++j) {
            v[j] = acc[i][j] + bv[j];
            ss += v[j] * v[j];
        }
        ss += __shfl_xor(ss, 1);
        ss += __shfl_xor(ss, 2);
        ss += __shfl_xor(ss, 4);
        ss += __shfl_xor(ss, 8);
        float norm = sqrtf(ss);
        float scale = (dg > 0.0f) ? (tanhf(norm) / fmaxf(norm, 1e-15f)) : 0.0f;

        float4 o0 = make_float4(v[0] * scale, v[1] * scale, v[2] * scale, v[3] * scale);
        float4 o1 = make_float4(v[4] * scale, v[5] * scale, v[6] * scale, v[7] * scale);
        *reinterpret_cast<float4*>(out + (size_t)m * D + tx * 8)     = o0;
        *reinterpret_cast<float4*>(out + (size_t)m * D + tx * 8 + 4) = o1;
    }
}

static inline size_t align256(size_t o) { return (o + 255) & ~(size_t)255; }

extern "C" void kernel_launch(void* const* d_in, const int* in_sizes, int n_in,
                              void* d_out, int out_size, void* d_ws, size_t ws_size,
                              hipStream_t stream) {
    const float* x   = (const float*)d_in[0];
    const float* W   = (const float*)d_in[1];
    const float* b   = (const float*)d_in[2];
    const int*   src = (const int*)d_in[3];
    const int*   dst = (const int*)d_in[4];
    float* out = (float*)d_out;

    int nNodes = in_sizes[0] / D;
    int nEdges = in_sizes[3];

    // workspace layout
    char* ws = (char*)d_ws;
    size_t off = 0;
    float* degf    = (float*)(ws + off); off = align256(off + sizeof(float) * nNodes);
    int*   count   = (int*)  (ws + off); off = align256(off + sizeof(int) * nNodes);
    int*   rowptr  = (int*)  (ws + off); off = align256(off + sizeof(int) * (nNodes + 1));
    int*   fill    = (int*)  (ws + off); off = align256(off + sizeof(int) * nNodes);
    float* scl     = (float*)(ws + off); off = align256(off + sizeof(float) * nNodes);
    int*   blksums = (int*)  (ws + off); off = align256(off + sizeof(int) * 256);
    int*   csr_src = (int*)  (ws + off); off = align256(off + sizeof(int) * nEdges);
    size_t required = off;

    float* msg = out;  // stage messages directly in d_out

    int numScanBlocks = (nNodes + 1023) / 1024;

    if (ws_size >= required && numScanBlocks <= 256) {
        // ---- CSR path (no float atomics) ----
        hipMemsetAsync(count, 0, sizeof(int) * nNodes, stream);
        hipMemsetAsync(fill,  0, sizeof(int) * nNodes, stream);

        int egrid = min(2048, (nEdges + 255) / 256);
        hist_kernel<<<egrid, 256, 0, stream>>>(dst, count, nEdges);
        scan_block_kernel<<<numScanBlocks, 256, 0, stream>>>(count, rowptr, blksums, nNodes);
        scan_totals_kernel<<<1, 256, 0, stream>>>(blksums, rowptr, numScanBlocks, nNodes, nEdges);
        add_offsets_kernel<<<(nNodes + 255) / 256, 256, 0, stream>>>(rowptr, blksums, nNodes);

        int winSize = (nNodes + 7) / 8;
        fill_kernel<<<4096, 256, 0, stream>>>(src, dst, rowptr, fill, csr_src, nEdges, winSize);

        scale_kernel<<<(nNodes + 3) / 4, 256, 0, stream>>>(x, scl, nNodes);
        gather_kernel<<<(nNodes + 3) / 4, 256, 0, stream>>>(x, scl, csr_src, rowptr, msg, degf, nNodes);
    } else {
        // ---- fallback: fp32 atomic scatter ----
        float* deg = (float*)d_ws;
        hipMemsetAsync(msg, 0, (size_t)nNodes * D * sizeof(float), stream);
        hipMemsetAsync(deg, 0, (size_t)nNodes * sizeof(float), stream);
        long long threads = (long long)nEdges * 32;
        int blocks = (int)((threads + 255) / 256);
        edge_scatter_kernel<<<blocks, 256, 0, stream>>>(x, src, dst, msg, (float*)d_ws, nEdges);
        degf = (float*)d_ws;
    }

    gemm_expmap_kernel<<<(nNodes + 63) / 64, 256, 0, stream>>>(msg, degf, W, b, out, nNodes);
}

// Round 4
// 274.450 us; speedup vs baseline: 10.3375x; 1.2926x over previous
//
#include <hip/hip_runtime.h>
#include <hip/hip_fp16.h>
#include <math.h>

constexpr int D = 128;

// ===========================================================================
// hist + position capture: count[d]++, epos[i] = old count (bucket position)
// ===========================================================================
__global__ __launch_bounds__(256) void hist_pos_kernel(
    const int* __restrict__ dst, int* __restrict__ count,
    int* __restrict__ epos, int nEdges)
{
    int stride = gridDim.x * blockDim.x;
    for (int i = blockIdx.x * blockDim.x + threadIdx.x; i < nEdges; i += stride)
        epos[i] = atomicAdd(&count[dst[i]], 1);
}

__global__ __launch_bounds__(256) void hist_kernel(
    const int* __restrict__ dst, int* __restrict__ count, int nEdges)
{
    int stride = gridDim.x * blockDim.x;
    for (int i = blockIdx.x * blockDim.x + threadIdx.x; i < nEdges; i += stride)
        atomicAdd(&count[dst[i]], 1);
}

// ===========================================================================
// two-level exclusive scan of count -> rowptr
// ===========================================================================
__global__ __launch_bounds__(256) void scan_block_kernel(
    const int* __restrict__ count, int* __restrict__ rowptr,
    int* __restrict__ blksums, int n)
{
    __shared__ int sums[256];
    int t = threadIdx.x;
    int base = blockIdx.x * 1024 + t * 4;
    int v[4];
    int s = 0;
#pragma unroll
    for (int j = 0; j < 4; ++j) { v[j] = (base + j < n) ? count[base + j] : 0; s += v[j]; }
    sums[t] = s;
    __syncthreads();
    for (int off = 1; off < 256; off <<= 1) {
        int xv = (t >= off) ? sums[t - off] : 0;
        __syncthreads();
        if (t >= off) sums[t] += xv;
        __syncthreads();
    }
    int run = (t > 0) ? sums[t - 1] : 0;
#pragma unroll
    for (int j = 0; j < 4; ++j) { if (base + j < n) rowptr[base + j] = run; run += v[j]; }
    if (t == 255) blksums[blockIdx.x] = sums[255];
}

__global__ __launch_bounds__(256) void scan_totals_kernel(
    int* __restrict__ blksums, int* __restrict__ rowptr,
    int numBlocks, int n, int E)
{
    __shared__ int s[256];
    int t = threadIdx.x;
    s[t] = (t < numBlocks) ? blksums[t] : 0;
    __syncthreads();
    for (int off = 1; off < 256; off <<= 1) {
        int xv = (t >= off) ? s[t - off] : 0;
        __syncthreads();
        if (t >= off) s[t] += xv;
        __syncthreads();
    }
    if (t < numBlocks) blksums[t] = (t > 0) ? s[t - 1] : 0;
    if (t == 0) rowptr[n] = E;
}

__global__ __launch_bounds__(256) void add_offsets_kernel(
    int* __restrict__ rowptr, const int* __restrict__ blksums, int n)
{
    int i = blockIdx.x * 256 + threadIdx.x;
    if (i < n) rowptr[i] += blksums[i >> 10];
}

// ===========================================================================
// fill, atomic-free (uses epos), XCD-windowed to keep csr writes L2-local
// ===========================================================================
__global__ __launch_bounds__(256) void fill_epos_kernel(
    const int* __restrict__ src, const int* __restrict__ dst,
    const int* __restrict__ rowptr, const int* __restrict__ epos,
    int* __restrict__ csr_src, int nEdges, int winSize)
{
    int pass  = blockIdx.x & 7;
    int slice = blockIdx.x >> 3;
    int nSlices = gridDim.x >> 3;
    int lo = pass * winSize;
    int hi = lo + winSize;

    int stride = nSlices * blockDim.x;
    for (int i = slice * blockDim.x + threadIdx.x; i < nEdges; i += stride) {
        int d = dst[i];
        if (d >= lo && d < hi)
            csr_src[rowptr[d] + epos[i]] = src[i];
    }
}

// fallback fill with atomics (no epos)
__global__ __launch_bounds__(256) void fill_kernel(
    const int* __restrict__ src, const int* __restrict__ dst,
    const int* __restrict__ rowptr, int* __restrict__ fill,
    int* __restrict__ csr_src, int nEdges, int winSize)
{
    int pass  = blockIdx.x & 7;
    int slice = blockIdx.x >> 3;
    int nSlices = gridDim.x >> 3;
    int lo = pass * winSize;
    int hi = lo + winSize;

    int stride = nSlices * blockDim.x;
    for (int i = slice * blockDim.x + threadIdx.x; i < nEdges; i += stride) {
        int d = dst[i];
        if (d >= lo && d < hi) {
            int pos = rowptr[d] + atomicAdd(&fill[d], 1);
            csr_src[pos] = src[i];
        }
    }
}

// ===========================================================================
// tangent_kernel: th[n][:] = fp16( arctanh(clip(||x||))/max(||x||,eps) * x )
// one wave per node, lane owns 2 elements
// ===========================================================================
__global__ __launch_bounds__(256) void tangent_kernel(
    const float* __restrict__ x, __half* __restrict__ th, int nNodes)
{
    int n    = (blockIdx.x * 256 + threadIdx.x) >> 6;
    int lane = threadIdx.x & 63;
    if (n >= nNodes) return;
    float2 xv = *reinterpret_cast<const float2*>(x + (size_t)n * D + lane * 2);
    float ss = xv.x * xv.x + xv.y * xv.y;
    ss += __shfl_xor(ss, 1);
    ss += __shfl_xor(ss, 2);
    ss += __shfl_xor(ss, 4);
    ss += __shfl_xor(ss, 8);
    ss += __shfl_xor(ss, 16);
    ss += __shfl_xor(ss, 32);
    float norm = sqrtf(ss);
    float ncl  = fminf(norm, 1.0f - 1e-7f);
    float at   = 0.5f * logf((1.0f + ncl) / (1.0f - ncl));
    float sc   = at / fmaxf(norm, 1e-15f);
    __half2 h = __float22half2_rn(make_float2(xv.x * sc, xv.y * sc));
    *(reinterpret_cast<__half2*>(th + (size_t)n * D) + lane) = h;
}

// scale-only (fp32 path)
__global__ __launch_bounds__(256) void scale_kernel(
    const float* __restrict__ x, float* __restrict__ scale, int nNodes)
{
    int node = (blockIdx.x * 256 + threadIdx.x) >> 6;
    int lane = threadIdx.x & 63;
    if (node >= nNodes) return;
    float2 xv = *reinterpret_cast<const float2*>(x + (size_t)node * D + lane * 2);
    float ss = xv.x * xv.x + xv.y * xv.y;
    ss += __shfl_xor(ss, 1);
    ss += __shfl_xor(ss, 2);
    ss += __shfl_xor(ss, 4);
    ss += __shfl_xor(ss, 8);
    ss += __shfl_xor(ss, 16);
    ss += __shfl_xor(ss, 32);
    if (lane == 0) {
        float norm = sqrtf(ss);
        float ncl  = fminf(norm, 1.0f - 1e-7f);
        float at   = 0.5f * logf((1.0f + ncl) / (1.0f - ncl));
        scale[node] = at / fmaxf(norm, 1e-15f);
    }
}

// ===========================================================================
// gather (fp16 rows): msg[n] = sum th[src_e]; degf[n] = deg
// 4 nodes per block (one wave each); lane owns half2 of D
// ===========================================================================
__global__ __launch_bounds__(256) void gather_h_kernel(
    const __half* __restrict__ th,
    const int* __restrict__ csr_src, const int* __restrict__ rowptr,
    float* __restrict__ msg, float* __restrict__ degf, int nNodes)
{
    int n    = blockIdx.x * 4 + (threadIdx.x >> 6);
    int lane = threadIdx.x & 63;
    if (n >= nNodes) return;

    int beg = rowptr[n], end = rowptr[n + 1];
    float2 acc0 = make_float2(0.0f, 0.0f);
    float2 acc1 = make_float2(0.0f, 0.0f);
    int e = beg;
    for (; e + 3 < end; e += 4) {
        int s0 = csr_src[e],     s1 = csr_src[e + 1];
        int s2 = csr_src[e + 2], s3 = csr_src[e + 3];
        __half2 a = *(reinterpret_cast<const __half2*>(th + (size_t)s0 * D) + lane);
        __half2 b = *(reinterpret_cast<const __half2*>(th + (size_t)s1 * D) + lane);
        __half2 c = *(reinterpret_cast<const __half2*>(th + (size_t)s2 * D) + lane);
        __half2 d = *(reinterpret_cast<const __half2*>(th + (size_t)s3 * D) + lane);
        float2 fa = __half22float2(a), fb = __half22float2(b);
        float2 fc = __half22float2(c), fd = __half22float2(d);
        acc0.x += fa.x; acc0.y += fa.y;
        acc1.x += fb.x; acc1.y += fb.y;
        acc0.x += fc.x; acc0.y += fc.y;
        acc1.x += fd.x; acc1.y += fd.y;
    }
    for (; e < end; ++e) {
        int s0 = csr_src[e];
        __half2 a = *(reinterpret_cast<const __half2*>(th + (size_t)s0 * D) + lane);
        float2 fa = __half22float2(a);
        acc0.x += fa.x; acc0.y += fa.y;
    }
    acc0.x += acc1.x;  acc0.y += acc1.y;
    *reinterpret_cast<float2*>(msg + (size_t)n * D + lane * 2) = acc0;
    if (lane == 0) degf[n] = (float)(end - beg);
}

// gather (fp32 rows, pre-scale multiplied on the fly) — mid tiers
__global__ __launch_bounds__(256) void gather_kernel(
    const float* __restrict__ x, const float* __restrict__ scale,
    const int* __restrict__ csr_src, const int* __restrict__ rowptr,
    float* __restrict__ msg, float* __restrict__ degf, int nNodes)
{
    int n    = blockIdx.x * 4 + (threadIdx.x >> 6);
    int lane = threadIdx.x & 63;
    if (n >= nNodes) return;

    int beg = rowptr[n], end = rowptr[n + 1];
    float2 acc0 = make_float2(0.0f, 0.0f);
    float2 acc1 = make_float2(0.0f, 0.0f);
    int e = beg;
    for (; e + 3 < end; e += 4) {
        int s0 = csr_src[e],     s1 = csr_src[e + 1];
        int s2 = csr_src[e + 2], s3 = csr_src[e + 3];
        float sc0 = scale[s0], sc1 = scale[s1];
        float sc2 = scale[s2], sc3 = scale[s3];
        float2 a = *reinterpret_cast<const float2*>(x + (size_t)s0 * D + lane * 2);
        float2 b = *reinterpret_cast<const float2*>(x + (size_t)s1 * D + lane * 2);
        float2 c = *reinterpret_cast<const float2*>(x + (size_t)s2 * D + lane * 2);
        float2 d = *reinterpret_cast<const float2*>(x + (size_t)s3 * D + lane * 2);
        acc0.x += sc0 * a.x;  acc0.y += sc0 * a.y;
        acc1.x += sc1 * b.x;  acc1.y += sc1 * b.y;
        acc0.x += sc2 * c.x;  acc0.y += sc2 * c.y;
        acc1.x += sc3 * d.x;  acc1.y += sc3 * d.y;
    }
    for (; e < end; ++e) {
        int s0 = csr_src[e];
        float sc0 = scale[s0];
        float2 a = *reinterpret_cast<const float2*>(x + (size_t)s0 * D + lane * 2);
        acc0.x += sc0 * a.x;  acc0.y += sc0 * a.y;
    }
    acc0.x += acc1.x;  acc0.y += acc1.y;
    *reinterpret_cast<float2*>(msg + (size_t)n * D + lane * 2) = acc0;
    if (lane == 0) degf[n] = (float)(end - beg);
}

// ===========================================================================
// Fallback edge scatter (fp32 hardware atomics) — last resort
// ===========================================================================
__global__ __launch_bounds__(256) void edge_scatter_kernel(
    const float* __restrict__ x,
    const int* __restrict__ src,
    const int* __restrict__ dst,
    float* __restrict__ msg,
    float* __restrict__ deg,
    int nEdges)
{
    long long t = (long long)blockIdx.x * blockDim.x + threadIdx.x;
    int edge = (int)(t >> 5);
    int lane = (int)(t & 31);
    if (edge >= nEdges) return;

    int s = src[edge];
    int d = dst[edge];

    const float4 xv = *reinterpret_cast<const float4*>(x + (size_t)s * D + lane * 4);
    float ss = xv.x * xv.x + xv.y * xv.y + xv.z * xv.z + xv.w * xv.w;
    ss += __shfl_xor(ss, 1);
    ss += __shfl_xor(ss, 2);
    ss += __shfl_xor(ss, 4);
    ss += __shfl_xor(ss, 8);
    ss += __shfl_xor(ss, 16);

    float norm = sqrtf(ss);
    float ncl  = fminf(norm, 1.0f - 1e-7f);
    float at   = 0.5f * logf((1.0f + ncl) / (1.0f - ncl));
    float scale = at / fmaxf(norm, 1e-15f);

    float* mrow = msg + (size_t)d * D + lane * 4;
    unsafeAtomicAdd(mrow + 0, xv.x * scale);
    unsafeAtomicAdd(mrow + 1, xv.y * scale);
    unsafeAtomicAdd(mrow + 2, xv.z * scale);
    unsafeAtomicAdd(mrow + 3, xv.w * scale);
    if (lane == 0) unsafeAtomicAdd(deg + d, 1.0f);
}

// ===========================================================================
// GEMM + expmap: out = expmap0( (msg/max(deg,1)) @ W^T + b ), 0 where deg==0
// ===========================================================================
__global__ __launch_bounds__(256) void gemm_expmap_kernel(
    const float* msg,
    const float* __restrict__ deg,
    const float* __restrict__ W,
    const float* __restrict__ bias,
    float* out,
    int nNodes)
{
    __shared__ float sA[64][68];
    __shared__ float sW[64][132];

    const int t  = threadIdx.x;
    const int tx = t & 15;
    const int ty = t >> 4;
    const int m0 = blockIdx.x * 64;

    float acc[4][8];
#pragma unroll
    for (int i = 0; i < 4; ++i)
#pragma unroll
        for (int j = 0; j < 8; ++j) acc[i][j] = 0.0f;

    for (int kc = 0; kc < D; kc += 64) {
#pragma unroll
        for (int p = 0; p < 4; ++p) {
            int ml = p * 16 + ty;
            int kl = tx * 4;
            int m  = m0 + ml;
            float4 v = make_float4(0.f, 0.f, 0.f, 0.f);
            if (m < nNodes) {
                v = *reinterpret_cast<const float4*>(msg + (size_t)m * D + kc + kl);
                float inv = 1.0f / fmaxf(deg[m], 1.0f);
                v.x *= inv; v.y *= inv; v.z *= inv; v.w *= inv;
            }
            *reinterpret_cast<float4*>(&sA[ml][kl]) = v;
        }
#pragma unroll
        for (int p = 0; p < 8; ++p) {
            int j  = p * 16 + ty;
            int kl = tx * 4;
            float4 v = *reinterpret_cast<const float4*>(W + (size_t)j * D + kc + kl);
            sW[kl + 0][j] = v.x;
            sW[kl + 1][j] = v.y;
            sW[kl + 2][j] = v.z;
            sW[kl + 3][j] = v.w;
        }
        __syncthreads();

        for (int k = 0; k < 64; ++k) {
            float a_[4];
#pragma unroll
            for (int i = 0; i < 4; ++i) a_[i] = sA[ty * 4 + i][k];
            float4 w0 = *reinterpret_cast<const float4*>(&sW[k][tx * 8]);
            float4 w1 = *reinterpret_cast<const float4*>(&sW[k][tx * 8 + 4]);
            float w_[8] = {w0.x, w0.y, w0.z, w0.w, w1.x, w1.y, w1.z, w1.w};
#pragma unroll
            for (int i = 0; i < 4; ++i)
#pragma unroll
                for (int j = 0; j < 8; ++j) acc[i][j] += a_[i] * w_[j];
        }
        __syncthreads();
    }

    float4 b0 = *reinterpret_cast<const float4*>(bias + tx * 8);
    float4 b1 = *reinterpret_cast<const float4*>(bias + tx * 8 + 4);
    float bv[8] = {b0.x, b0.y, b0.z, b0.w, b1.x, b1.y, b1.z, b1.w};

#pragma unroll
    for (int i = 0; i < 4; ++i) {
        int m = m0 + ty * 4 + i;
        if (m >= nNodes) continue;
        float dg = deg[m];
        float v[8];
        float ss = 0.0f;
#pragma unroll
        for (int j = 0; j < 8; ++j) {
            v[j] = acc[i][j] + bv[j];
            ss += v[j] * v[j];
        }
        ss += __shfl_xor(ss, 1);
        ss += __shfl_xor(ss, 2);
        ss += __shfl_xor(ss, 4);
        ss += __shfl_xor(ss, 8);
        float norm = sqrtf(ss);
        float scale = (dg > 0.0f) ? (tanhf(norm) / fmaxf(norm, 1e-15f)) : 0.0f;

        float4 o0 = make_float4(v[0] * scale, v[1] * scale, v[2] * scale, v[3] * scale);
        float4 o1 = make_float4(v[4] * scale, v[5] * scale, v[6] * scale, v[7] * scale);
        *reinterpret_cast<float4*>(out + (size_t)m * D + tx * 8)     = o0;
        *reinterpret_cast<float4*>(out + (size_t)m * D + tx * 8 + 4) = o1;
    }
}

static inline size_t align256(size_t o) { return (o + 255) & ~(size_t)255; }

extern "C" void kernel_launch(void* const* d_in, const int* in_sizes, int n_in,
                              void* d_out, int out_size, void* d_ws, size_t ws_size,
                              hipStream_t stream) {
    const float* x   = (const float*)d_in[0];
    const float* W   = (const float*)d_in[1];
    const float* b   = (const float*)d_in[2];
    const int*   src = (const int*)d_in[3];
    const int*   dst = (const int*)d_in[4];
    float* out = (float*)d_out;

    int nNodes = in_sizes[0] / D;
    int nEdges = in_sizes[3];

    // workspace layout (tiered)
    char* ws = (char*)d_ws;
    size_t off = 0;
    float* degf    = (float*)(ws + off); off = align256(off + sizeof(float) * nNodes);
    int*   count   = (int*)  (ws + off); off = align256(off + sizeof(int) * nNodes);
    int*   rowptr  = (int*)  (ws + off); off = align256(off + sizeof(int) * (nNodes + 1));
    int*   fillc   = (int*)  (ws + off); off = align256(off + sizeof(int) * nNodes);
    float* scl     = (float*)(ws + off); off = align256(off + sizeof(float) * nNodes);
    int*   blksums = (int*)  (ws + off); off = align256(off + sizeof(int) * 256);
    int*   csr_src = (int*)  (ws + off); off = align256(off + sizeof(int) * nEdges);
    size_t need_base = off;
    int*   epos    = (int*)  (ws + off); off = align256(off + sizeof(int) * nEdges);
    size_t need_epos = off;
    __half* th     = (__half*)(ws + off); off = align256(off + sizeof(__half) * (size_t)nNodes * D);
    size_t need_th = off;

    float* msg = out;  // stage messages directly in d_out (fp32, same rows)

    int numScanBlocks = (nNodes + 1023) / 1024;
    bool csr_ok  = (ws_size >= need_base) && (numScanBlocks <= 256);
    bool use_epos = (ws_size >= need_epos) && csr_ok;
    bool use_fp16 = (ws_size >= need_th) && use_epos;

    if (csr_ok) {
        hipMemsetAsync(count, 0, sizeof(int) * nNodes, stream);
        if (!use_epos) hipMemsetAsync(fillc, 0, sizeof(int) * nNodes, stream);

        int egrid = min(2048, (nEdges + 255) / 256);
        if (use_epos)
            hist_pos_kernel<<<egrid, 256, 0, stream>>>(dst, count, epos, nEdges);
        else
            hist_kernel<<<egrid, 256, 0, stream>>>(dst, count, nEdges);

        scan_block_kernel<<<numScanBlocks, 256, 0, stream>>>(count, rowptr, blksums, nNodes);
        scan_totals_kernel<<<1, 256, 0, stream>>>(blksums, rowptr, numScanBlocks, nNodes, nEdges);
        add_offsets_kernel<<<(nNodes + 255) / 256, 256, 0, stream>>>(rowptr, blksums, nNodes);

        int winSize = (nNodes + 7) / 8;
        if (use_epos)
            fill_epos_kernel<<<4096, 256, 0, stream>>>(src, dst, rowptr, epos, csr_src, nEdges, winSize);
        else
            fill_kernel<<<4096, 256, 0, stream>>>(src, dst, rowptr, fillc, csr_src, nEdges, winSize);

        if (use_fp16) {
            tangent_kernel<<<(nNodes + 3) / 4, 256, 0, stream>>>(x, th, nNodes);
            gather_h_kernel<<<(nNodes + 3) / 4, 256, 0, stream>>>(th, csr_src, rowptr, msg, degf, nNodes);
        } else {
            scale_kernel<<<(nNodes + 3) / 4, 256, 0, stream>>>(x, scl, nNodes);
            gather_kernel<<<(nNodes + 3) / 4, 256, 0, stream>>>(x, scl, csr_src, rowptr, msg, degf, nNodes);
        }
    } else {
        float* deg = (float*)d_ws;
        hipMemsetAsync(msg, 0, (size_t)nNodes * D * sizeof(float), stream);
        hipMemsetAsync(deg, 0, (size_t)nNodes * sizeof(float), stream);
        long long threads = (long long)nEdges * 32;
        int blocks = (int)((threads + 255) / 256);
        edge_scatter_kernel<<<blocks, 256, 0, stream>>>(x, src, dst, msg, (float*)d_ws, nEdges);
        degf = (float*)d_ws;
    }

    gemm_expmap_kernel<<<(nNodes + 63) / 64, 256, 0, stream>>>(msg, degf, W, b, out, nNodes);
}

// Round 5
// 211.987 us; speedup vs baseline: 13.3834x; 1.2947x over previous
//
#include <hip/hip_runtime.h>
#include <hip/hip_fp16.h>
#include <math.h>

constexpr int D = 128;

typedef __attribute__((ext_vector_type(8))) short bf16x8;
typedef __attribute__((ext_vector_type(4))) float f32x4;

__device__ inline short f2bf(float f) {
    unsigned u = __builtin_bit_cast(unsigned, f);
    u = (u + 0x7FFFu + ((u >> 16) & 1u)) >> 16;   // round-to-nearest-even
    return (short)u;
}

// ===========================================================================
// hist + position capture: count[d]++, epos[i] = old count (bucket position)
// ===========================================================================
__global__ __launch_bounds__(256) void hist_pos_kernel(
    const int* __restrict__ dst, int* __restrict__ count,
    int* __restrict__ epos, int nEdges)
{
    int stride = gridDim.x * blockDim.x;
    for (int i = blockIdx.x * blockDim.x + threadIdx.x; i < nEdges; i += stride)
        epos[i] = atomicAdd(&count[dst[i]], 1);
}

__global__ __launch_bounds__(256) void hist_kernel(
    const int* __restrict__ dst, int* __restrict__ count, int nEdges)
{
    int stride = gridDim.x * blockDim.x;
    for (int i = blockIdx.x * blockDim.x + threadIdx.x; i < nEdges; i += stride)
        atomicAdd(&count[dst[i]], 1);
}

// ===========================================================================
// two-level exclusive scan of count -> rowptr
// ===========================================================================
__global__ __launch_bounds__(256) void scan_block_kernel(
    const int* __restrict__ count, int* __restrict__ rowptr,
    int* __restrict__ blksums, int n)
{
    __shared__ int sums[256];
    int t = threadIdx.x;
    int base = blockIdx.x * 1024 + t * 4;
    int v[4];
    int s = 0;
#pragma unroll
    for (int j = 0; j < 4; ++j) { v[j] = (base + j < n) ? count[base + j] : 0; s += v[j]; }
    sums[t] = s;
    __syncthreads();
    for (int off = 1; off < 256; off <<= 1) {
        int xv = (t >= off) ? sums[t - off] : 0;
        __syncthreads();
        if (t >= off) sums[t] += xv;
        __syncthreads();
    }
    int run = (t > 0) ? sums[t - 1] : 0;
#pragma unroll
    for (int j = 0; j < 4; ++j) { if (base + j < n) rowptr[base + j] = run; run += v[j]; }
    if (t == 255) blksums[blockIdx.x] = sums[255];
}

__global__ __launch_bounds__(256) void scan_totals_kernel(
    int* __restrict__ blksums, int* __restrict__ rowptr,
    int numBlocks, int n, int E)
{
    __shared__ int s[256];
    int t = threadIdx.x;
    s[t] = (t < numBlocks) ? blksums[t] : 0;
    __syncthreads();
    for (int off = 1; off < 256; off <<= 1) {
        int xv = (t >= off) ? s[t - off] : 0;
        __syncthreads();
        if (t >= off) s[t] += xv;
        __syncthreads();
    }
    if (t < numBlocks) blksums[t] = (t > 0) ? s[t - 1] : 0;
    if (t == 0) rowptr[n] = E;
}

__global__ __launch_bounds__(256) void add_offsets_kernel(
    int* __restrict__ rowptr, const int* __restrict__ blksums, int n)
{
    int i = blockIdx.x * 256 + threadIdx.x;
    if (i < n) rowptr[i] += blksums[i >> 10];
}

// ===========================================================================
// fill, atomic-free (uses epos), XCD-windowed to keep csr writes L2-local
// ===========================================================================
__global__ __launch_bounds__(256) void fill_epos_kernel(
    const int* __restrict__ src, const int* __restrict__ dst,
    const int* __restrict__ rowptr, const int* __restrict__ epos,
    int* __restrict__ csr_src, int nEdges, int winSize)
{
    int pass  = blockIdx.x & 7;
    int slice = blockIdx.x >> 3;
    int nSlices = gridDim.x >> 3;
    int lo = pass * winSize;
    int hi = lo + winSize;

    int stride = nSlices * blockDim.x;
    for (int i = slice * blockDim.x + threadIdx.x; i < nEdges; i += stride) {
        int d = dst[i];
        if (d >= lo && d < hi)
            csr_src[rowptr[d] + epos[i]] = src[i];
    }
}

__global__ __launch_bounds__(256) void fill_kernel(
    const int* __restrict__ src, const int* __restrict__ dst,
    const int* __restrict__ rowptr, int* __restrict__ fill,
    int* __restrict__ csr_src, int nEdges, int winSize)
{
    int pass  = blockIdx.x & 7;
    int slice = blockIdx.x >> 3;
    int nSlices = gridDim.x >> 3;
    int lo = pass * winSize;
    int hi = lo + winSize;

    int stride = nSlices * blockDim.x;
    for (int i = slice * blockDim.x + threadIdx.x; i < nEdges; i += stride) {
        int d = dst[i];
        if (d >= lo && d < hi) {
            int pos = rowptr[d] + atomicAdd(&fill[d], 1);
            csr_src[pos] = src[i];
        }
    }
}

// ===========================================================================
// tangent_kernel: th[n][:] = fp16( arctanh(clip(||x||))/max(||x||,eps) * x )
// ===========================================================================
__global__ __launch_bounds__(256) void tangent_kernel(
    const float* __restrict__ x, __half* __restrict__ th, int nNodes)
{
    int n    = (blockIdx.x * 256 + threadIdx.x) >> 6;
    int lane = threadIdx.x & 63;
    if (n >= nNodes) return;
    float2 xv = *reinterpret_cast<const float2*>(x + (size_t)n * D + lane * 2);
    float ss = xv.x * xv.x + xv.y * xv.y;
    ss += __shfl_xor(ss, 1);
    ss += __shfl_xor(ss, 2);
    ss += __shfl_xor(ss, 4);
    ss += __shfl_xor(ss, 8);
    ss += __shfl_xor(ss, 16);
    ss += __shfl_xor(ss, 32);
    float norm = sqrtf(ss);
    float ncl  = fminf(norm, 1.0f - 1e-7f);
    float at   = 0.5f * logf((1.0f + ncl) / (1.0f - ncl));
    float sc   = at / fmaxf(norm, 1e-15f);
    __half2 h = __float22half2_rn(make_float2(xv.x * sc, xv.y * sc));
    *(reinterpret_cast<__half2*>(th + (size_t)n * D) + lane) = h;
}

__global__ __launch_bounds__(256) void scale_kernel(
    const float* __restrict__ x, float* __restrict__ scale, int nNodes)
{
    int node = (blockIdx.x * 256 + threadIdx.x) >> 6;
    int lane = threadIdx.x & 63;
    if (node >= nNodes) return;
    float2 xv = *reinterpret_cast<const float2*>(x + (size_t)node * D + lane * 2);
    float ss = xv.x * xv.x + xv.y * xv.y;
    ss += __shfl_xor(ss, 1);
    ss += __shfl_xor(ss, 2);
    ss += __shfl_xor(ss, 4);
    ss += __shfl_xor(ss, 8);
    ss += __shfl_xor(ss, 16);
    ss += __shfl_xor(ss, 32);
    if (lane == 0) {
        float norm = sqrtf(ss);
        float ncl  = fminf(norm, 1.0f - 1e-7f);
        float at   = 0.5f * logf((1.0f + ncl) / (1.0f - ncl));
        scale[node] = at / fmaxf(norm, 1e-15f);
    }
}

// ===========================================================================
// gather (fp16 rows, 16-lane rows): 4 groups/wave, 16B/lane, 8 rows in flight
// ===========================================================================
__global__ __launch_bounds__(256) void gather_h16_kernel(
    const __half* __restrict__ th,
    const int* __restrict__ csr_src, const int* __restrict__ rowptr,
    float* __restrict__ msg, float* __restrict__ degf, int nNodes)
{
    int n    = blockIdx.x * 4 + (threadIdx.x >> 6);
    int lane = threadIdx.x & 63;
    if (n >= nNodes) return;
    int grp = lane >> 4;      // 0..3 : this group's edge slots k = grp, grp+4, ...
    int sl  = lane & 15;      // owns elements [8*sl, 8*sl+8)

    int beg = rowptr[n];
    int cnt = rowptr[n + 1] - beg;

    float acc[8];
#pragma unroll
    for (int j = 0; j < 8; ++j) acc[j] = 0.0f;

    int k = grp;
    for (; k + 4 < cnt; k += 8) {
        int s0 = csr_src[beg + k];
        int s1 = csr_src[beg + k + 4];
        float4 r0 = *reinterpret_cast<const float4*>(th + (size_t)s0 * D + sl * 8);
        float4 r1 = *reinterpret_cast<const float4*>(th + (size_t)s1 * D + sl * 8);
        const __half2* h0 = reinterpret_cast<const __half2*>(&r0);
        const __half2* h1 = reinterpret_cast<const __half2*>(&r1);
#pragma unroll
        for (int j = 0; j < 4; ++j) {
            float2 f0 = __half22float2(h0[j]);
            float2 f1 = __half22float2(h1[j]);
            acc[2 * j]     += f0.x + f1.x;
            acc[2 * j + 1] += f0.y + f1.y;
        }
    }
    for (; k < cnt; k += 4) {
        int s0 = csr_src[beg + k];
        float4 r0 = *reinterpret_cast<const float4*>(th + (size_t)s0 * D + sl * 8);
        const __half2* h0 = reinterpret_cast<const __half2*>(&r0);
#pragma unroll
        for (int j = 0; j < 4; ++j) {
            float2 f0 = __half22float2(h0[j]);
            acc[2 * j]     += f0.x;
            acc[2 * j + 1] += f0.y;
        }
    }
    // combine the 4 groups
#pragma unroll
    for (int j = 0; j < 8; ++j) {
        acc[j] += __shfl_xor(acc[j], 16);
        acc[j] += __shfl_xor(acc[j], 32);
    }
    if (grp == 0) {
        float4 o0 = make_float4(acc[0], acc[1], acc[2], acc[3]);
        float4 o1 = make_float4(acc[4], acc[5], acc[6], acc[7]);
        *reinterpret_cast<float4*>(msg + (size_t)n * D + sl * 8)     = o0;
        *reinterpret_cast<float4*>(msg + (size_t)n * D + sl * 8 + 4) = o1;
        if (lane == 0) degf[n] = (float)cnt;
    }
}

// gather (fp32 rows) — mid tier
__global__ __launch_bounds__(256) void gather_kernel(
    const float* __restrict__ x, const float* __restrict__ scale,
    const int* __restrict__ csr_src, const int* __restrict__ rowptr,
    float* __restrict__ msg, float* __restrict__ degf, int nNodes)
{
    int n    = blockIdx.x * 4 + (threadIdx.x >> 6);
    int lane = threadIdx.x & 63;
    if (n >= nNodes) return;

    int beg = rowptr[n], end = rowptr[n + 1];
    float2 acc0 = make_float2(0.0f, 0.0f);
    float2 acc1 = make_float2(0.0f, 0.0f);
    int e = beg;
    for (; e + 3 < end; e += 4) {
        int s0 = csr_src[e],     s1 = csr_src[e + 1];
        int s2 = csr_src[e + 2], s3 = csr_src[e + 3];
        float sc0 = scale[s0], sc1 = scale[s1];
        float sc2 = scale[s2], sc3 = scale[s3];
        float2 a = *reinterpret_cast<const float2*>(x + (size_t)s0 * D + lane * 2);
        float2 b = *reinterpret_cast<const float2*>(x + (size_t)s1 * D + lane * 2);
        float2 c = *reinterpret_cast<const float2*>(x + (size_t)s2 * D + lane * 2);
        float2 d = *reinterpret_cast<const float2*>(x + (size_t)s3 * D + lane * 2);
        acc0.x += sc0 * a.x;  acc0.y += sc0 * a.y;
        acc1.x += sc1 * b.x;  acc1.y += sc1 * b.y;
        acc0.x += sc2 * c.x;  acc0.y += sc2 * c.y;
        acc1.x += sc3 * d.x;  acc1.y += sc3 * d.y;
    }
    for (; e < end; ++e) {
        int s0 = csr_src[e];
        float sc0 = scale[s0];
        float2 a = *reinterpret_cast<const float2*>(x + (size_t)s0 * D + lane * 2);
        acc0.x += sc0 * a.x;  acc0.y += sc0 * a.y;
    }
    acc0.x += acc1.x;  acc0.y += acc1.y;
    *reinterpret_cast<float2*>(msg + (size_t)n * D + lane * 2) = acc0;
    if (lane == 0) degf[n] = (float)(end - beg);
}

// ===========================================================================
// Fallback edge scatter (fp32 hardware atomics) — last resort
// ===========================================================================
__global__ __launch_bounds__(256) void edge_scatter_kernel(
    const float* __restrict__ x,
    const int* __restrict__ src,
    const int* __restrict__ dst,
    float* __restrict__ msg,
    float* __restrict__ deg,
    int nEdges)
{
    long long t = (long long)blockIdx.x * blockDim.x + threadIdx.x;
    int edge = (int)(t >> 5);
    int lane = (int)(t & 31);
    if (edge >= nEdges) return;

    int s = src[edge];
    int d = dst[edge];

    const float4 xv = *reinterpret_cast<const float4*>(x + (size_t)s * D + lane * 4);
    float ss = xv.x * xv.x + xv.y * xv.y + xv.z * xv.z + xv.w * xv.w;
    ss += __shfl_xor(ss, 1);
    ss += __shfl_xor(ss, 2);
    ss += __shfl_xor(ss, 4);
    ss += __shfl_xor(ss, 8);
    ss += __shfl_xor(ss, 16);

    float norm = sqrtf(ss);
    float ncl  = fminf(norm, 1.0f - 1e-7f);
    float at   = 0.5f * logf((1.0f + ncl) / (1.0f - ncl));
    float scale = at / fmaxf(norm, 1e-15f);

    float* mrow = msg + (size_t)d * D + lane * 4;
    unsafeAtomicAdd(mrow + 0, xv.x * scale);
    unsafeAtomicAdd(mrow + 1, xv.y * scale);
    unsafeAtomicAdd(mrow + 2, xv.z * scale);
    unsafeAtomicAdd(mrow + 3, xv.w * scale);
    if (lane == 0) unsafeAtomicAdd(deg + d, 1.0f);
}

// ===========================================================================
// MFMA bf16 GEMM + expmap: out = expmap0( (msg@W^T)/max(deg,1) + b ),
// zeroed where deg==0. msg fp32 (aliases out), converted to bf16 fragments
// in-register; W staged once per block as bf16 in LDS ([128][136] pad).
// Block = 4 waves x 16 rows = 64 rows; wave covers 16 rows x 128 cols.
// mfma_f32_16x16x32_bf16: A lane=row(l&15),k=(l>>4)*8+i; B lane=col(l&15),
// same k; D col=lane&15, row=(lane>>4)*4+reg  (m89-verified).
// In-place safe: each wave's A-reads (its 16 rows) precede its stores.
// ===========================================================================
__global__ __launch_bounds__(256) void gemm_mfma_kernel(
    const float* msg, const float* __restrict__ deg,
    const float* __restrict__ W, const float* __restrict__ bias,
    float* out, int nNodes)
{
    __shared__ short sW[128][136];   // bf16 bits, +8 pad => <=2-way conflicts

    const int t = threadIdx.x;

    // stage W -> bf16 LDS (each thread: 16 float4 chunks)
#pragma unroll
    for (int p = 0; p < 16; ++p) {
        int chunk = p * 256 + t;            // 4096 chunks of 4 floats
        int row = chunk >> 5;
        int c4  = (chunk & 31) * 4;
        float4 v = *reinterpret_cast<const float4*>(W + row * 128 + c4);
        short4 s;
        s.x = f2bf(v.x); s.y = f2bf(v.y); s.z = f2bf(v.z); s.w = f2bf(v.w);
        *reinterpret_cast<short4*>(&sW[row][c4]) = s;
    }
    __syncthreads();

    const int wave = t >> 6;
    const int lane = t & 63;
    const int l15  = lane & 15;
    const int lhi  = lane >> 4;
    const int m0   = blockIdx.x * 64 + wave * 16;

    // A fragments: row m0+l15, k-chunks kc*32 + lhi*8 (+i)
    int arow = m0 + l15;
    if (arow >= nNodes) arow = nNodes - 1;      // clamp: results discarded
    const float* ap = msg + (size_t)arow * D + lhi * 8;
    bf16x8 a[4];
#pragma unroll
    for (int kc = 0; kc < 4; ++kc) {
        float4 v0 = *reinterpret_cast<const float4*>(ap + kc * 32);
        float4 v1 = *reinterpret_cast<const float4*>(ap + kc * 32 + 4);
        bf16x8 f;
        f[0] = f2bf(v0.x); f[1] = f2bf(v0.y); f[2] = f2bf(v0.z); f[3] = f2bf(v0.w);
        f[4] = f2bf(v1.x); f[5] = f2bf(v1.y); f[6] = f2bf(v1.z); f[7] = f2bf(v1.w);
        a[kc] = f;
    }

    f32x4 acc[8];
#pragma unroll
    for (int ct = 0; ct < 8; ++ct) acc[ct] = (f32x4){0.f, 0.f, 0.f, 0.f};

#pragma unroll
    for (int ct = 0; ct < 8; ++ct) {
#pragma unroll
        for (int kc = 0; kc < 4; ++kc) {
            bf16x8 bfrag = *reinterpret_cast<const bf16x8*>(
                &sW[ct * 16 + l15][kc * 32 + lhi * 8]);
            acc[ct] = __builtin_amdgcn_mfma_f32_16x16x32_bf16(a[kc], bfrag, acc[ct], 0, 0, 0);
        }
    }

    // epilogue
    float bv[8];
#pragma unroll
    for (int ct = 0; ct < 8; ++ct) bv[ct] = bias[ct * 16 + l15];

#pragma unroll
    for (int r = 0; r < 4; ++r) {
        int row = m0 + lhi * 4 + r;
        int rc  = row < nNodes ? row : nNodes - 1;
        float dg  = deg[rc];
        float inv = 1.0f / fmaxf(dg, 1.0f);
        float v[8];
        float ss = 0.0f;
#pragma unroll
        for (int ct = 0; ct < 8; ++ct) {
            v[ct] = acc[ct][r] * inv + bv[ct];
            ss += v[ct] * v[ct];
        }
        ss += __shfl_xor(ss, 1);
        ss += __shfl_xor(ss, 2);
        ss += __shfl_xor(ss, 4);
        ss += __shfl_xor(ss, 8);
        float norm = sqrtf(ss);
        float sc = (dg > 0.0f) ? (tanhf(norm) / fmaxf(norm, 1e-15f)) : 0.0f;
        if (row < nNodes) {
#pragma unroll
            for (int ct = 0; ct < 8; ++ct)
                out[(size_t)row * D + ct * 16 + l15] = v[ct] * sc;
        }
    }
}

static inline size_t align256(size_t o) { return (o + 255) & ~(size_t)255; }

extern "C" void kernel_launch(void* const* d_in, const int* in_sizes, int n_in,
                              void* d_out, int out_size, void* d_ws, size_t ws_size,
                              hipStream_t stream) {
    const float* x   = (const float*)d_in[0];
    const float* W   = (const float*)d_in[1];
    const float* b   = (const float*)d_in[2];
    const int*   src = (const int*)d_in[3];
    const int*   dst = (const int*)d_in[4];
    float* out = (float*)d_out;

    int nNodes = in_sizes[0] / D;
    int nEdges = in_sizes[3];

    // workspace layout (tiered)
    char* ws = (char*)d_ws;
    size_t off = 0;
    float* degf    = (float*)(ws + off); off = align256(off + sizeof(float) * nNodes);
    int*   count   = (int*)  (ws + off); off = align256(off + sizeof(int) * nNodes);
    int*   rowptr  = (int*)  (ws + off); off = align256(off + sizeof(int) * (nNodes + 1));
    int*   fillc   = (int*)  (ws + off); off = align256(off + sizeof(int) * nNodes);
    float* scl     = (float*)(ws + off); off = align256(off + sizeof(float) * nNodes);
    int*   blksums = (int*)  (ws + off); off = align256(off + sizeof(int) * 256);
    int*   csr_src = (int*)  (ws + off); off = align256(off + sizeof(int) * nEdges);
    size_t need_base = off;
    int*   epos    = (int*)  (ws + off); off = align256(off + sizeof(int) * nEdges);
    size_t need_epos = off;
    __half* th     = (__half*)(ws + off); off = align256(off + sizeof(__half) * (size_t)nNodes * D);
    size_t need_th = off;

    float* msg = out;  // stage messages directly in d_out (fp32, same rows)

    int numScanBlocks = (nNodes + 1023) / 1024;
    bool csr_ok   = (ws_size >= need_base) && (numScanBlocks <= 256);
    bool use_epos = (ws_size >= need_epos) && csr_ok;
    bool use_fp16 = (ws_size >= need_th) && use_epos;

    if (csr_ok) {
        hipMemsetAsync(count, 0, sizeof(int) * nNodes, stream);
        if (!use_epos) hipMemsetAsync(fillc, 0, sizeof(int) * nNodes, stream);

        int egrid = min(2048, (nEdges + 255) / 256);
        if (use_epos)
            hist_pos_kernel<<<egrid, 256, 0, stream>>>(dst, count, epos, nEdges);
        else
            hist_kernel<<<egrid, 256, 0, stream>>>(dst, count, nEdges);

        scan_block_kernel<<<numScanBlocks, 256, 0, stream>>>(count, rowptr, blksums, nNodes);
        scan_totals_kernel<<<1, 256, 0, stream>>>(blksums, rowptr, numScanBlocks, nNodes, nEdges);
        add_offsets_kernel<<<(nNodes + 255) / 256, 256, 0, stream>>>(rowptr, blksums, nNodes);

        int winSize = (nNodes + 7) / 8;
        if (use_epos)
            fill_epos_kernel<<<4096, 256, 0, stream>>>(src, dst, rowptr, epos, csr_src, nEdges, winSize);
        else
            fill_kernel<<<4096, 256, 0, stream>>>(src, dst, rowptr, fillc, csr_src, nEdges, winSize);

        if (use_fp16) {
            tangent_kernel<<<(nNodes + 3) / 4, 256, 0, stream>>>(x, th, nNodes);
            gather_h16_kernel<<<(nNodes + 3) / 4, 256, 0, stream>>>(th, csr_src, rowptr, msg, degf, nNodes);
        } else {
            scale_kernel<<<(nNodes + 3) / 4, 256, 0, stream>>>(x, scl, nNodes);
            gather_kernel<<<(nNodes + 3) / 4, 256, 0, stream>>>(x, scl, csr_src, rowptr, msg, degf, nNodes);
        }
    } else {
        float* deg = (float*)d_ws;
        hipMemsetAsync(msg, 0, (size_t)nNodes * D * sizeof(float), stream);
        hipMemsetAsync(deg, 0, (size_t)nNodes * sizeof(float), stream);
        long long threads = (long long)nEdges * 32;
        int blocks = (int)((threads + 255) / 256);
        edge_scatter_kernel<<<blocks, 256, 0, stream>>>(x, src, dst, msg, (float*)d_ws, nEdges);
        degf = (float*)d_ws;
    }

    gemm_mfma_kernel<<<(nNodes + 63) / 64, 256, 0, stream>>>(msg, degf, W, b, out, nNodes);
}